// Round 4
// baseline (118.796 us; speedup 1.0000x reference)
//
#include <hip/hip_runtime.h>
#include <math.h>

#define N_INW     1024
#define N_DEPTH   8
#define N_GROW    512
#define N_BATCH   4096
#define N_THREADS 128    // 2 independent waves/WG; wave cp owns its own slab
#define SLAB_B    19584  // (4608 + 288 pad) * 4 B per wave

typedef __attribute__((ext_vector_type(2))) float    F2;
typedef __attribute__((ext_vector_type(2))) _Float16 h2;

// fp16 slab (per wave): row r -> half2 at byte (r + (r>>4))<<2.
#define ADDR(r) ((((r) + ((r) >> 4))) << 2)

#define LDH(A)    __builtin_bit_cast(h2, *(const unsigned*)(L + (A)))
#define STH(A, V) do { *(unsigned*)(L + (A)) =                                 \
                       __builtin_bit_cast(unsigned, (V)); } while (0)

#define PKU(x, y) __builtin_bit_cast(unsigned int,                             \
                      __builtin_amdgcn_cvt_pkrtz((x), (y)))

// broadcast lo/hi half of a packed uint (2 halves) into both lanes of an h2
#define BCL(U) ({ h2 _t = __builtin_bit_cast(h2, (unsigned)(U));               \
                  h2 _r; _r.x = _t.x; _r.y = _t.x; _r; })
#define BCH(U) ({ h2 _t = __builtin_bit_cast(h2, (unsigned)(U));               \
                  h2 _r; _r.x = _t.y; _r.y = _t.y; _r; })

// native packed-f16 2x2 rotation: v_pk_mul_f16 / v_pk_fma_f16
#define ROTPH(LO, HI, CC, SS) do { h2 _l = LO, _h = HI, _c = CC, _s = SS;      \
    LO = _c * _l + _s * _h; HI = _c * _h - _s * _l; } while (0)

// ---- per-set register state (A / B ping-pong, full-module prefetch) ----
#define DECL_SET(P)                                                            \
    uint4 P##c0, P##s0, P##c1, P##s1, P##c2, P##s2, P##c3, P##s3,              \
          P##c4, P##s4, P##c5, P##s5, P##c6, P##s6, P##c7, P##s7;              \
    int4  P##i0, P##i1, P##i2, P##i3;                                          \
    float4 P##bA, P##bB;

// synthesize one packed cs layer from angles (in-kernel; no workspace)
#define SYN1(P, K, ANB) do {                                                   \
    const float4* _p = (const float4*)((ANB) + (K)*512 + (blk << 3));          \
    float4 _u = _p[0], _v = _p[1];                                             \
    float _c0,_c1,_c2,_c3,_c4,_c5,_c6,_c7,_t0,_t1,_t2,_t3,_t4,_t5,_t6,_t7;     \
    __sincosf(_u.x,&_t0,&_c0); __sincosf(_u.y,&_t1,&_c1);                      \
    __sincosf(_u.z,&_t2,&_c2); __sincosf(_u.w,&_t3,&_c3);                      \
    __sincosf(_v.x,&_t4,&_c4); __sincosf(_v.y,&_t5,&_c5);                      \
    __sincosf(_v.z,&_t6,&_c6); __sincosf(_v.w,&_t7,&_c7);                      \
    P##c##K = make_uint4(PKU(_c0,_c1),PKU(_c2,_c3),PKU(_c4,_c5),PKU(_c6,_c7)); \
    P##s##K = make_uint4(PKU(_t0,_t1),PKU(_t2,_t3),PKU(_t4,_t5),PKU(_t6,_t7)); \
  } while (0)

#define LOADCS8(P, ANB) do {                                                   \
    SYN1(P,0,ANB); SYN1(P,1,ANB); SYN1(P,2,ANB); SYN1(P,3,ANB);                \
    SYN1(P,4,ANB); SYN1(P,5,ANB); SYN1(P,6,ANB); SYN1(P,7,ANB); } while (0)
#define LOADCS4(P, ANB) do {                                                   \
    SYN1(P,0,ANB); SYN1(P,1,ANB); SYN1(P,2,ANB); SYN1(P,3,ANB); } while (0)

#define TR(v) (((v) + ((v) >> 4)) << 2)
#define LOAD_AB(P, INB, BIN) do {                                              \
    const int4* _ip = (const int4*)((INB) + (blk << 4));                       \
    int4 _v0=_ip[0], _v1=_ip[1], _v2=_ip[2], _v3=_ip[3];                       \
    P##i0.x=TR(_v0.x); P##i0.y=TR(_v0.y); P##i0.z=TR(_v0.z); P##i0.w=TR(_v0.w);\
    P##i1.x=TR(_v1.x); P##i1.y=TR(_v1.y); P##i1.z=TR(_v1.z); P##i1.w=TR(_v1.w);\
    P##i2.x=TR(_v2.x); P##i2.y=TR(_v2.y); P##i2.z=TR(_v2.z); P##i2.w=TR(_v2.w);\
    P##i3.x=TR(_v3.x); P##i3.y=TR(_v3.y); P##i3.z=TR(_v3.z); P##i3.w=TR(_v3.w);\
    const float4* _bp = (const float4*)((BIN) + (blk << 3));                   \
    P##bA = _bp[0]; P##bB = _bp[1]; } while (0)

// rotation layers consuming PACKED cs (value j: j0=lo(x),j1=hi(x),...,j7=hi(w))
#define HROTS1(C,S) do {                                                       \
    ROTPH(x0,x1,  BCL(C.x),BCL(S.x)); ROTPH(x2,x3,  BCH(C.x),BCH(S.x));        \
    ROTPH(x4,x5,  BCL(C.y),BCL(S.y)); ROTPH(x6,x7,  BCH(C.y),BCH(S.y));        \
    ROTPH(x8,x9,  BCL(C.z),BCL(S.z)); ROTPH(x10,x11,BCH(C.z),BCH(S.z));        \
    ROTPH(x12,x13,BCL(C.w),BCL(S.w)); ROTPH(x14,x15,BCH(C.w),BCH(S.w));        \
  } while (0)
#define HROTS2(C,S) do {                                                       \
    ROTPH(x0,x2,  BCL(C.x),BCL(S.x)); ROTPH(x1,x3,  BCH(C.x),BCH(S.x));        \
    ROTPH(x4,x6,  BCL(C.y),BCL(S.y)); ROTPH(x5,x7,  BCH(C.y),BCH(S.y));        \
    ROTPH(x8,x10, BCL(C.z),BCL(S.z)); ROTPH(x9,x11, BCH(C.z),BCH(S.z));        \
    ROTPH(x12,x14,BCL(C.w),BCL(S.w)); ROTPH(x13,x15,BCH(C.w),BCH(S.w));        \
  } while (0)
#define HROTS4(C,S) do {                                                       \
    ROTPH(x0,x4,  BCL(C.x),BCL(S.x)); ROTPH(x1,x5,  BCH(C.x),BCH(S.x));        \
    ROTPH(x2,x6,  BCL(C.y),BCL(S.y)); ROTPH(x3,x7,  BCH(C.y),BCH(S.y));        \
    ROTPH(x8,x12, BCL(C.z),BCL(S.z)); ROTPH(x9,x13, BCH(C.z),BCH(S.z));        \
    ROTPH(x10,x14,BCL(C.w),BCL(S.w)); ROTPH(x11,x15,BCH(C.w),BCH(S.w));        \
  } while (0)
#define HROTS8(C,S) do {                                                       \
    ROTPH(x0,x8,  BCL(C.x),BCL(S.x)); ROTPH(x1,x9,  BCH(C.x),BCH(S.x));        \
    ROTPH(x2,x10, BCL(C.y),BCL(S.y)); ROTPH(x3,x11, BCH(C.y),BCH(S.y));        \
    ROTPH(x4,x12, BCL(C.z),BCL(S.z)); ROTPH(x5,x13, BCH(C.z),BCH(S.z));        \
    ROTPH(x6,x14, BCL(C.w),BCL(S.w)); ROTPH(x7,x15, BCH(C.w),BCH(S.w));        \
  } while (0)

#define HROT(P, K, M) M(P##c##K, P##s##K)

// activation in fp32 (values are h2 in registers; bias fp32 scalar per row)
#define ACTH(X, BF) do {                                                       \
    float _lo = (float)(X).x + (BF), _hi = (float)(X).y + (BF);                \
    _lo = 0.5f * (_lo + __builtin_amdgcn_sqrtf(_lo * _lo + 1.0f));             \
    _hi = 0.5f * (_hi + __builtin_amdgcn_sqrtf(_hi * _hi + 1.0f));             \
    X = __builtin_bit_cast(h2, PKU(_lo, _hi)); } while (0)

#define FENCE() __builtin_amdgcn_sched_barrier(0)

// process module M with set P; prefetch next module into set N (FULL=all 8
// layers, else IN 4 only). Barrier-free (each wave owns its private slab);
// fenced load blocks keep full-module prefetch distance.
#define PROC_MOD(P, N, ANN, INB, BIN, M, FULL) do {                            \
  const int a0=P##i0.x, a1=P##i0.y, a2=P##i0.z, a3=P##i0.w,                    \
            a4=P##i1.x, a5=P##i1.y, a6=P##i1.z, a7=P##i1.w,                    \
            a8=P##i2.x, a9=P##i2.y, a10=P##i2.z, a11=P##i2.w,                  \
            a12=P##i3.x, a13=P##i3.y, a14=P##i3.z, a15=P##i3.w;                \
  h2 x0=LDH(a0), x1=LDH(a1), x2=LDH(a2), x3=LDH(a3),                           \
     x4=LDH(a4), x5=LDH(a5), x6=LDH(a6), x7=LDH(a7),                           \
     x8=LDH(a8), x9=LDH(a9), x10=LDH(a10), x11=LDH(a11),                       \
     x12=LDH(a12), x13=LDH(a13), x14=LDH(a14), x15=LDH(a15);                   \
  if (FULL) { LOADCS8(N, ANN); } else { LOADCS4(N, ANN); }                     \
  FENCE();                                                                     \
  HROT(P,0,HROTS1); HROT(P,1,HROTS2); HROT(P,2,HROTS4); HROT(P,3,HROTS8);      \
  ACTH(x0,P##bA.x); ACTH(x1,P##bA.y); ACTH(x2,P##bA.z); ACTH(x3,P##bA.w);      \
  ACTH(x4,P##bB.x); ACTH(x5,P##bB.y); ACTH(x6,P##bB.z); ACTH(x7,P##bB.w);      \
  const int _ab = ADDR(N_INW + (M)*N_GROW + (blk << 3));                       \
  STH(_ab+ 0,x0); STH(_ab+ 4,x1); STH(_ab+ 8,x2); STH(_ab+12,x3);              \
  STH(_ab+16,x4); STH(_ab+20,x5); STH(_ab+24,x6); STH(_ab+28,x7);              \
  LOAD_AB(N, INB, BIN);                                                        \
  FENCE();                                                                     \
  HROT(P,4,HROTS1); HROT(P,5,HROTS2); HROT(P,6,HROTS4); HROT(P,7,HROTS8);      \
  STH(a0,x0);  STH(a1,x1);  STH(a2,x2);  STH(a3,x3);                           \
  STH(a4,x4);  STH(a5,x5);  STH(a6,x6);  STH(a7,x7);                           \
  STH(a8,x8);  STH(a9,x9);  STH(a10,x10); STH(a11,x11);                        \
  STH(a12,x12); STH(a13,x13); STH(a14,x14); STH(a15,x15);                      \
} while (0)

__global__ __launch_bounds__(N_THREADS, 2)   // <=256 VGPR
void butterfly_fused_kernel(const float* __restrict__ input,
                            const float* __restrict__ scales,
                            const float* __restrict__ biases,
                            const int*   __restrict__ indices,
                            const float* __restrict__ angles,
                            float* __restrict__ out) {
    extern __shared__ float ldsbuf[];
    const int t   = threadIdx.x;
    const int blk = t & 63;          // butterfly block = lane
    const int cp  = t >> 6;          // wave id; waves fully independent
    char* L = (char*)ldsbuf + cp * SLAB_B;   // private per-wave slab
    const int b   = blockIdx.x;
    // XCD swizzle: blockIdx%8 == x owns columns [x*512,(x+1)*512)
    const int cg  = ((((b & 7) * 128) + (b >> 3)) << 2) + (cp << 1);

    DECL_SET(A) DECL_SET(B)

    // prologue: module 0 params into A
    LOADCS8(A, angles);
    LOAD_AB(A, indices, biases);

    // init: rows 0..1023 = scales[r] * input[r][cg..cg+1] (fp16 pack)
#pragma unroll
    for (int k = 0; k < 16; ++k) {
        const int r = (k << 6) + blk;
        F2 v = *(const F2*)(input + (size_t)r * N_BATCH + cg);
        STH(ADDR(r), __builtin_bit_cast(h2, PKU(scales[r] * v.x, scales[r] * v.y)));
    }

    // next-module bases (module 1)
    const float* ann = angles + 4096;
    const int*   inb = indices + N_INW;
    const float* bin = biases + N_GROW;

#pragma unroll 1
    for (int tt = 0; tt < 3; ++tt) {
        const int m = 2 * tt;
        PROC_MOD(A, B, ann, inb, bin, m, 1);
        ann += 4096; inb += N_INW; bin += N_GROW;
        PROC_MOD(B, A, ann, inb, bin, m + 1, 1);
        ann += 4096; inb += N_INW; bin += N_GROW;
    }
    // module 6 (A), prefetching module 7's IN layers into B
    PROC_MOD(A, B, ann, inb, bin, 6, 0);

    // epilogue: module 7 (B) — OUT rotations + scatter are dead code;
    // output = module-7 activations (convert fp16 -> fp32).
    {
        h2 x0=LDH(Bi0.x), x1=LDH(Bi0.y), x2=LDH(Bi0.z), x3=LDH(Bi0.w),
           x4=LDH(Bi1.x), x5=LDH(Bi1.y), x6=LDH(Bi1.z), x7=LDH(Bi1.w),
           x8=LDH(Bi2.x), x9=LDH(Bi2.y), x10=LDH(Bi2.z), x11=LDH(Bi2.w),
           x12=LDH(Bi3.x), x13=LDH(Bi3.y), x14=LDH(Bi3.z), x15=LDH(Bi3.w);
        FENCE();
        HROT(B,0,HROTS1); HROT(B,1,HROTS2); HROT(B,2,HROTS4); HROT(B,3,HROTS8);
        ACTH(x0,BbA.x); ACTH(x1,BbA.y); ACTH(x2,BbA.z); ACTH(x3,BbA.w);
        ACTH(x4,BbB.x); ACTH(x5,BbB.y); ACTH(x6,BbB.z); ACTH(x7,BbB.w);
#define OUTW(J, X) do { F2 _o; _o.x = (float)(X).x; _o.y = (float)(X).y;       \
        *(F2*)(out + (size_t)((blk<<3)+(J))*N_BATCH + cg) = _o; } while (0)
        OUTW(0,x0); OUTW(1,x1); OUTW(2,x2); OUTW(3,x3);
        OUTW(4,x4); OUTW(5,x5); OUTW(6,x6); OUTW(7,x7);
#undef OUTW
    }
}

// ---------------- host ----------------
// Workspace-free: the harness re-poisons d_ws (256 MiB fill, ~43 us) every
// iteration when the kernel uses it. In-kernel sincos (~512/wave) is far
// cheaper than that fill. d_ws is deliberately untouched.
extern "C" void kernel_launch(void* const* d_in, const int* in_sizes, int n_in,
                              void* d_out, int out_size, void* d_ws, size_t ws_size,
                              hipStream_t stream) {
    const float* input   = (const float*)d_in[0];
    const float* scales  = (const float*)d_in[1];
    const float* angles  = (const float*)d_in[2];
    const float* biases  = (const float*)d_in[3];
    const int*   indices = (const int*)d_in[4];
    float* out = (float*)d_out;

    const size_t lds_bytes = (size_t)2 * SLAB_B;                         // 39168 B
    const int grid = N_BATCH / 4;                                        // 1024 WGs

    butterfly_fused_kernel<<<grid, N_THREADS, lds_bytes, stream>>>(
        input, scales, biases, indices, angles, out);
}

// Round 5
// 104.748 us; speedup vs baseline: 1.1341x; 1.1341x over previous
//
#include <hip/hip_runtime.h>
#include <math.h>

#define N_INW   1024
#define N_DEPTH 8
#define N_GROW  512
#define N_BATCH 4096
#define N_ROWS  4608            // slab rows; module-7 act goes straight to out
#define COLSTR  9220            // bytes/column: 4608*2 + 4 -> 2305 dwords (odd: bank-spread)
#define LDS_B   (16 * COLSTR)   // 147520 B (<160 KiB)
#define MAT_B   ((size_t)N_DEPTH * 64 * 2 * 512)        // 512 KiB fragment-ordered mats
#define ADR_OFF MAT_B
#define WS_NEED (MAT_B + (size_t)N_DEPTH * 1024 * 2)

typedef __attribute__((ext_vector_type(4))) _Float16 h4;
typedef __attribute__((ext_vector_type(4))) float    f4;
typedef __attribute__((ext_vector_type(2))) unsigned u32x2;

#define PKU(x, y) __builtin_bit_cast(unsigned int,                             \
                      __builtin_amdgcn_cvt_pkrtz((x), (y)))

// ---- precompute: compose each half-module into a dense 16x16 f16 matrix ----
// Record (m, b, half): 512 B, A-fragment order for v_mfma_f32_16x16x16_f16:
//   lane l holds A[row = l&15][k = (l>>4)*4 + h], h = half-index 0..3.
// Plus u16 LDS byte-offsets (2*row) for gather/scatter.
__global__ void precompute_kernel(const float* __restrict__ angles,
                                  const int*   __restrict__ indices,
                                  char* __restrict__ ws) {
    int id = blockIdx.x * blockDim.x + threadIdx.x;
    if (id < 16384) {             // one thread = one column k of one matrix
        int k = id & 15, b = (id >> 4) & 63, half = (id >> 10) & 1, m = id >> 11;
        float v[16];
#pragma unroll
        for (int i = 0; i < 16; ++i) v[i] = (i == k) ? 1.f : 0.f;
#pragma unroll
        for (int lp = 0; lp < 4; ++lp) {          // strides 1,2,4,8
            int s = 1 << lp;
            const float* ab = angles + m * 4096 + (half * 4 + lp) * 512 + b * 8;
#pragma unroll
            for (int p = 0; p < 8; ++p) {         // angle idx = b*8 + p (derived)
                int q = p >> lp, r = p & (s - 1);
                int lo = q * 2 * s + r, hi = lo + s;
                float a = ab[p], c, sn;
                __sincosf(a, &sn, &c);
                float nl = c * v[lo] + sn * v[hi];
                float nh = c * v[hi] - sn * v[lo];
                v[lo] = nl; v[hi] = nh;
            }
        }
        char* rec = ws + (((size_t)(m * 64 + b) * 2 + half) << 9);
#pragma unroll
        for (int row = 0; row < 16; ++row) {
            int lane = ((k >> 2) << 4) | row;
            *(unsigned short*)(rec + lane * 8 + (k & 3) * 2) =
                __builtin_bit_cast(unsigned short, (_Float16)v[row]);
        }
    }
    if (id < 8192) {              // [m][16b+k] -> LDS byte offset (2*row)
        ((unsigned short*)(ws + ADR_OFF))[id] =
            (unsigned short)(indices[(id >> 10) * N_INW + (id & 1023)] << 1);
    }
}

__device__ __forceinline__ float actf(float x) {
    return 0.5f * (x + __builtin_amdgcn_sqrtf(x * x + 1.0f));
}

#define DECLSET(P) h4 P##ai[8], P##ao[8]; u32x2 P##ad[8];

#define LOADSET(P, M) do {                                                     \
    _Pragma("unroll")                                                          \
    for (int bb = 0; bb < 8; ++bb) {                                           \
        const char* rb = mats + (((size_t)((M) * 64 + wblk0 + bb) * 2) << 9);  \
        P##ai[bb] = *(const h4*)(rb + lane * 8);                               \
        P##ao[bb] = *(const h4*)(rb + 512 + lane * 8);                         \
        P##ad[bb] = *(const u32x2*)(adr + ((M) * 64 + wblk0 + bb) * 16 + (q << 2)); \
    } } while (0)

// one module: gather all blocks first (deep LDS pipelining), then
// MFMA(in) -> act -> MFMA(out) -> scatter per block. One barrier per module.
#define PROC(P, NP, M, LAST) do {                                              \
  if (!(LAST)) LOADSET(NP, (M) + 1);                                           \
  u32x2 bw[8];                                                                 \
  _Pragma("unroll")                                                            \
  for (int bb = 0; bb < 8; ++bb) {                                             \
    u32x2 ad = P##ad[bb];                                                      \
    unsigned g0 = *(const unsigned short*)(L + cB + (ad.x & 0xffffu));         \
    unsigned g1 = *(const unsigned short*)(L + cB + (ad.x >> 16));             \
    unsigned g2 = *(const unsigned short*)(L + cB + (ad.y & 0xffffu));         \
    unsigned g3 = *(const unsigned short*)(L + cB + (ad.y >> 16));             \
    bw[bb].x = g0 | (g1 << 16); bw[bb].y = g2 | (g3 << 16);                    \
  }                                                                            \
  _Pragma("unroll")                                                            \
  for (int bb = 0; bb < 8; ++bb) {                                             \
    const int blk = wblk0 + bb;                                                \
    f4 cin = f4zero;                                                           \
    if (q < 2)                                                                 \
        cin = *(const f4*)(biases + (M) * N_GROW + blk * 8 + ((q & 1) << 2));  \
    f4 d = __builtin_amdgcn_mfma_f32_16x16x16f16(                              \
               P##ai[bb], __builtin_bit_cast(h4, bw[bb]), cin, 0, 0, 0);       \
    if (q < 2) {                                                               \
        d.x = actf(d.x); d.y = actf(d.y); d.z = actf(d.z); d.w = actf(d.w);    \
    }                                                                          \
    if (LAST) {                                                                \
        if (q < 2) {                                                           \
            float* op = out + (size_t)(blk * 8 + (q << 2)) * N_BATCH + cg + c; \
            op[0] = d.x; op[N_BATCH] = d.y;                                    \
            op[2 * N_BATCH] = d.z; op[3 * N_BATCH] = d.w;                      \
        }                                                                      \
    } else {                                                                   \
        unsigned p0 = PKU(d.x, d.y), p1 = PKU(d.z, d.w);                       \
        if (q < 2) {  /* activation rows into act region */                    \
            char* ap = L + cB +                                                \
                ((N_INW + (M) * N_GROW + blk * 8 + (q << 2)) << 1);            \
            *(unsigned*)ap = p0; *(unsigned*)(ap + 4) = p1;                    \
        }                                                                      \
        u32x2 bp; bp.x = p0; bp.y = p1;                                        \
        f4 d2 = __builtin_amdgcn_mfma_f32_16x16x16f16(                         \
                    P##ao[bb], __builtin_bit_cast(h4, bp), f4zero, 0, 0, 0);   \
        u32x2 ad = P##ad[bb];                                                  \
        *(unsigned short*)(L + cB + (ad.x & 0xffffu)) =                        \
            __builtin_bit_cast(unsigned short, (_Float16)d2.x);                \
        *(unsigned short*)(L + cB + (ad.x >> 16)) =                            \
            __builtin_bit_cast(unsigned short, (_Float16)d2.y);                \
        *(unsigned short*)(L + cB + (ad.y & 0xffffu)) =                        \
            __builtin_bit_cast(unsigned short, (_Float16)d2.z);                \
        *(unsigned short*)(L + cB + (ad.y >> 16)) =                            \
            __builtin_bit_cast(unsigned short, (_Float16)d2.w);                \
    }                                                                          \
  }                                                                            \
  if (!(LAST)) __syncthreads();                                                \
} while (0)

__global__ __launch_bounds__(512, 2)
void butterfly_mfma_kernel(const float* __restrict__ input,
                           const float* __restrict__ scales,
                           const float* __restrict__ biases,
                           const char*  __restrict__ mats,
                           const unsigned short* __restrict__ adr,
                           float* __restrict__ out) {
    extern __shared__ char L[];
    const int t = threadIdx.x, lane = t & 63, w = t >> 6;
    const int c = lane & 15, q = lane >> 4;      // col-in-tile, k-group
    const int cB = c * COLSTR;                   // column slab base (bytes)
    const int wblk0 = w * 8;                     // this wave's 8 blocks
    const int cg = blockIdx.x * 16;              // global column base
    const f4 f4zero = {0.f, 0.f, 0.f, 0.f};

    DECLSET(A) DECLSET(B)
    LOADSET(A, 0);

    // init rows 0..1023: slab[c][r] = f16(scales[r] * input[r][cg+c])
    {
        const int rg = (t >> 4) * 32;            // 32 rowgroups x 16 cols
        const int ci = t & 15;
#pragma unroll
        for (int i = 0; i < 32; i += 2) {
            int r = rg + i;
            float v0 = input[(size_t)r * N_BATCH + cg + ci] * scales[r];
            float v1 = input[(size_t)(r + 1) * N_BATCH + cg + ci] * scales[r + 1];
            *(unsigned*)(L + ci * COLSTR + (r << 1)) = PKU(v0, v1);
        }
    }
    __syncthreads();

#pragma unroll 1
    for (int tt = 0; tt < 3; ++tt) {
        PROC(A, B, 2 * tt, 0);
        PROC(B, A, 2 * tt + 1, 0);
    }
    PROC(A, B, 6, 0);
    PROC(B, B, 7, 1);   // module 7: act rows -> global out (f32), no scatter
}

// ---------------- host ----------------
// The harness re-poisons d_ws unconditionally every iteration (round-4
// evidence: overhead identical with zero workspace use), so workspace-based
// precompute is free. 512 KiB composed matrices + 16 KiB addr table.
extern "C" void kernel_launch(void* const* d_in, const int* in_sizes, int n_in,
                              void* d_out, int out_size, void* d_ws, size_t ws_size,
                              hipStream_t stream) {
    const float* input   = (const float*)d_in[0];
    const float* scales  = (const float*)d_in[1];
    const float* angles  = (const float*)d_in[2];
    const float* biases  = (const float*)d_in[3];
    const int*   indices = (const int*)d_in[4];
    float* out = (float*)d_out;

    precompute_kernel<<<64, 256, 0, stream>>>(angles, indices, (char*)d_ws);
    butterfly_mfma_kernel<<<256, 512, LDS_B, stream>>>(
        input, scales, biases, (const char*)d_ws,
        (const unsigned short*)((char*)d_ws + ADR_OFF), out);
}

// Round 6
// 102.705 us; speedup vs baseline: 1.1567x; 1.0199x over previous
//
#include <hip/hip_runtime.h>
#include <math.h>

#define N_INW   1024
#define N_DEPTH 8
#define N_GROW  512
#define N_BATCH 4096
#define COLSTR  9220            // bytes/col: 4608*2+4 -> 2305 dwords (odd: bank-spread)
#define LDS_B   (16 * COLSTR)   // 147520 B (< 160 KiB)
#define MAT_B   ((size_t)N_DEPTH * 64 * 1024)   // 512 KiB: 1024 B per (m, block)
#define ADR_OFF MAT_B                            // + 32 KiB u32 addr table

typedef __attribute__((ext_vector_type(4))) _Float16 h4;
typedef __attribute__((ext_vector_type(4))) float    f4;
typedef __attribute__((ext_vector_type(2))) float    F2;
typedef __attribute__((ext_vector_type(2))) unsigned u2;

#define PKU(x, y) __builtin_bit_cast(unsigned,                                 \
                      __builtin_amdgcn_cvt_pkrtz((x), (y)))

// ---- precompute: compose each half-module into a dense 16x16 f16 matrix ----
// Record (m, b): 1024 B. Lane l holds bytes l*16: [A_in frag 8 B | A_out frag 8 B]
// where frag element e (e=0..3) = M[row = l&15][k = (l>>4)*4 + e]  (HW-verified
// A-layout from round 5). Addr table: u32 byte-offset (row<<1) per (m, b, k).
__global__ void precompute_kernel(const float* __restrict__ angles,
                                  const int*   __restrict__ indices,
                                  char* __restrict__ ws) {
    int id = blockIdx.x * blockDim.x + threadIdx.x;
    if (id < 16384) {             // one thread = one column k of one 16x16 matrix
        int k = id & 15, b = (id >> 4) & 63, half = (id >> 10) & 1, m = id >> 11;
        float v[16];
#pragma unroll
        for (int i = 0; i < 16; ++i) v[i] = (i == k) ? 1.f : 0.f;
#pragma unroll
        for (int lp = 0; lp < 4; ++lp) {          // strides 1,2,4,8
            int s = 1 << lp;
            const float* ab = angles + m * 4096 + (half * 4 + lp) * 512 + b * 8;
#pragma unroll
            for (int p = 0; p < 8; ++p) {
                int qq = p >> lp, r = p & (s - 1);
                int lo = qq * 2 * s + r, hi = lo + s;
                float a = ab[p], c, sn;
                __sincosf(a, &sn, &c);
                float nl = c * v[lo] + sn * v[hi];
                float nh = c * v[hi] - sn * v[lo];
                v[lo] = nl; v[hi] = nh;
            }
        }
        char* rec = ws + ((size_t)(m * 64 + b) << 10);
#pragma unroll
        for (int row = 0; row < 16; ++row) {
            int lane = ((k >> 2) << 4) | row;
            *(unsigned short*)(rec + lane * 16 + half * 8 + (k & 3) * 2) =
                __builtin_bit_cast(unsigned short, (_Float16)v[row]);
        }
    }
    if (id < 8192) {              // [m][b*16+k] -> u32 LDS byte offset (2*row)
        ((unsigned*)(ws + ADR_OFF))[id] =
            (unsigned)(indices[(id >> 10) * N_INW + (id & 1023)] << 1);
    }
}

__device__ __forceinline__ float actf(float x) {
    return 0.5f * (x + __builtin_amdgcn_sqrtf(x * x + 1.0f));
}

#define DECLSET(P) h4 P##ai[8], P##ao[8]; uint4 P##ad[8];

// one 16-B mats load + one 16-B addr load per block per lane
#define LOADSET(P, M) do {                                                     \
    _Pragma("unroll")                                                          \
    for (int bb = 0; bb < 8; ++bb) {                                           \
        const int rb = (M) * 64 + wblk0 + bb;                                  \
        uint4 rc = *(const uint4*)(mats + ((size_t)rb << 10) + (lane << 4));   \
        u2 t0; t0.x = rc.x; t0.y = rc.y;                                       \
        u2 t1; t1.x = rc.z; t1.y = rc.w;                                       \
        P##ai[bb] = __builtin_bit_cast(h4, t0);                                \
        P##ao[bb] = __builtin_bit_cast(h4, t1);                                \
        P##ad[bb] = *(const uint4*)(adr + (size_t)rb * 64 + (q << 4));         \
    } } while (0)

// one module: gather all blocks (max LDS ILP), then per block:
// MFMA(in) -> act -> MFMA(out) -> scatter. One barrier per module.
#define PROC(P, NP, M, LAST) do {                                              \
  if (!(LAST)) LOADSET(NP, (M) + 1);                                           \
  u2 bw[8];                                                                    \
  _Pragma("unroll")                                                            \
  for (int bb = 0; bb < 8; ++bb) {                                             \
    uint4 ad = P##ad[bb];                                                      \
    unsigned g0 = *(const unsigned short*)(L + cB + ad.x);                     \
    unsigned g1 = *(const unsigned short*)(L + cB + ad.y);                     \
    unsigned g2 = *(const unsigned short*)(L + cB + ad.z);                     \
    unsigned g3 = *(const unsigned short*)(L + cB + ad.w);                     \
    bw[bb].x = g0 | (g1 << 16); bw[bb].y = g2 | (g3 << 16);                    \
  }                                                                            \
  __builtin_amdgcn_s_setprio(1);                                               \
  _Pragma("unroll")                                                            \
  for (int bb = 0; bb < 8; ++bb) {                                             \
    const int blk = wblk0 + bb;                                                \
    f4 cin = f4zero;                                                           \
    if (q < 2)                                                                 \
        cin = *(const f4*)(biases + (M) * N_GROW + blk * 8 + ((q & 1) << 2));  \
    f4 d = __builtin_amdgcn_mfma_f32_16x16x16f16(                              \
               P##ai[bb], __builtin_bit_cast(h4, bw[bb]), cin, 0, 0, 0);       \
    if (q < 2) {                                                               \
        d.x = actf(d.x); d.y = actf(d.y); d.z = actf(d.z); d.w = actf(d.w);    \
    }                                                                          \
    if (LAST) {                                                                \
        if (q < 2) {                                                           \
            float* op = out + (size_t)(blk * 8 + (q << 2)) * N_BATCH + cg + c; \
            op[0] = d.x; op[N_BATCH] = d.y;                                    \
            op[2 * N_BATCH] = d.z; op[3 * N_BATCH] = d.w;                      \
        }                                                                      \
    } else {                                                                   \
        unsigned p0 = PKU(d.x, d.y), p1 = PKU(d.z, d.w);                       \
        if (q < 2) {  /* activation rows into act region (canonical rows) */   \
            char* ap = L + cB +                                                \
                ((N_INW + (M) * N_GROW + blk * 8 + (q << 2)) << 1);            \
            *(unsigned*)ap = p0; *(unsigned*)(ap + 4) = p1;                    \
        }                                                                      \
        u2 bp; bp.x = p0; bp.y = p1;                                           \
        f4 d2 = __builtin_amdgcn_mfma_f32_16x16x16f16(                         \
                    P##ao[bb], __builtin_bit_cast(h4, bp), f4zero, 0, 0, 0);   \
        uint4 ad = P##ad[bb];                                                  \
        *(unsigned short*)(L + cB + ad.x) =                                    \
            __builtin_bit_cast(unsigned short, (_Float16)d2.x);                \
        *(unsigned short*)(L + cB + ad.y) =                                    \
            __builtin_bit_cast(unsigned short, (_Float16)d2.y);                \
        *(unsigned short*)(L + cB + ad.z) =                                    \
            __builtin_bit_cast(unsigned short, (_Float16)d2.z);                \
        *(unsigned short*)(L + cB + ad.w) =                                    \
            __builtin_bit_cast(unsigned short, (_Float16)d2.w);                \
    }                                                                          \
  }                                                                            \
  __builtin_amdgcn_s_setprio(0);                                               \
  if (!(LAST)) __syncthreads();                                                \
} while (0)

__global__ __launch_bounds__(512, 2)
void butterfly_mfma_kernel(const float* __restrict__ input,
                           const float* __restrict__ scales,
                           const float* __restrict__ biases,
                           const char*  __restrict__ mats,
                           const char*  __restrict__ adr,
                           float* __restrict__ out) {
    extern __shared__ char L[];
    const int t = threadIdx.x, lane = t & 63, w = t >> 6;
    const int c = lane & 15, q = lane >> 4;      // col-in-tile, k-group
    const int cB = c * COLSTR;                   // column slab base (bytes)
    const int wblk0 = w * 8;                     // this wave's 8 blocks
    const int cg = blockIdx.x * 16;              // global column base
    const f4 f4zero = {0.f, 0.f, 0.f, 0.f};

    DECLSET(A) DECLSET(B)
    LOADSET(A, 0);

    // init rows 0..1023, vectorized: thread = (col-pair, 16-row group)
    {
        const int cp = (t & 7) << 1;             // columns cp, cp+1
        const int r0 = (t >> 3) << 4;            // rows r0..r0+15
#pragma unroll
        for (int i = 0; i < 16; i += 2) {
            int r = r0 + i;
            F2 w0 = *(const F2*)(input + (size_t)r * N_BATCH + cg + cp);
            F2 w1 = *(const F2*)(input + (size_t)(r + 1) * N_BATCH + cg + cp);
            F2 sc = *(const F2*)(scales + r);
            *(unsigned*)(L + cp * COLSTR + (r << 1))       = PKU(sc.x * w0.x, sc.y * w1.x);
            *(unsigned*)(L + (cp + 1) * COLSTR + (r << 1)) = PKU(sc.x * w0.y, sc.y * w1.y);
        }
    }
    __syncthreads();

#pragma unroll 1
    for (int tt = 0; tt < 3; ++tt) {
        PROC(A, B, 2 * tt, 0);
        PROC(B, A, 2 * tt + 1, 0);
    }
    PROC(A, B, 6, 0);
    PROC(B, B, 7, 1);   // module 7: activations -> global out (f32), no scatter
}

// ---------------- host ----------------
// The harness re-poisons d_ws unconditionally every iteration (round-4
// evidence), so workspace-based precompute is free. 512 KiB matrices +
// 32 KiB addr table.
extern "C" void kernel_launch(void* const* d_in, const int* in_sizes, int n_in,
                              void* d_out, int out_size, void* d_ws, size_t ws_size,
                              hipStream_t stream) {
    const float* input   = (const float*)d_in[0];
    const float* scales  = (const float*)d_in[1];
    const float* angles  = (const float*)d_in[2];
    const float* biases  = (const float*)d_in[3];
    const int*   indices = (const int*)d_in[4];
    float* out = (float*)d_out;

    precompute_kernel<<<64, 256, 0, stream>>>(angles, indices, (char*)d_ws);
    butterfly_mfma_kernel<<<256, 512, LDS_B, stream>>>(
        input, scales, biases, (const char*)d_ws,
        (const char*)d_ws + ADR_OFF, out);
}